// Round 1
// baseline (475.565 us; speedup 1.0000x reference)
//
#include <hip/hip_runtime.h>
#include <math.h>

// Problem constants (fixed by setup_inputs)
constexpr int B    = 2;
constexpr int W    = 16;
constexpr int N    = 1000;
constexpr int FIN  = 16;
constexpr int E    = 16000;
constexpr int DE   = 8;
constexpr int H    = 128;   // hidden
constexpr int NH   = 4;     // heads
constexpr int DK   = 32;    // head dim
constexpr int L    = 3;
// Window pruning: only global windows 12..15 matter (temporal edges go t -> t+1,
// head reads only w=15, 3 layers => 3 hops back + input).
constexpr int WL   = 4;          // local windows kept (global 12..15)
constexpr int W0G  = 12;         // first kept global window
constexpr int RPB  = WL * N;     // rows per batch = 4000
constexpr int ROWS = B * RPB;    // 8000

// ---------------- helpers ----------------
__device__ __forceinline__ float blockSum128(float v) {
  #pragma unroll
  for (int off = 32; off >= 1; off >>= 1) v += __shfl_xor(v, off);
  __shared__ float s2[2];
  int w = threadIdx.x >> 6;
  __syncthreads();  // protect s2 reuse across multiple calls
  if ((threadIdx.x & 63) == 0) s2[w] = v;
  __syncthreads();
  return s2[0] + s2[1];
}

// ---------------- graph prep ----------------
__global__ void k_mean_ea(const float* __restrict__ ea, float* __restrict__ meanea) {
  __shared__ float sbuf[256];
  int t = threadIdx.x;
  int d = t & 7, g = t >> 3;  // 32 groups x 8 attrs
  float s = 0.f;
  for (int e = g; e < E; e += 32) s += ea[e * DE + d];
  sbuf[t] = s;
  __syncthreads();
  for (int st = 16; st >= 1; st >>= 1) {
    if (g < st) sbuf[g * 8 + d] += sbuf[(g + st) * 8 + d];
    __syncthreads();
  }
  if (g == 0) meanea[d] = sbuf[d] * (1.0f / E);
}

__global__ void k_count(const int* __restrict__ ei, int* __restrict__ counts) {
  int e = blockIdx.x * blockDim.x + threadIdx.x;
  if (e < E) atomicAdd(&counts[ei[E + e]], 1);
}

__global__ void k_scan(const int* __restrict__ counts, int* __restrict__ offs,
                       int* __restrict__ cursor) {
  __shared__ int s[1024];
  int t = threadIdx.x;
  int v = (t < N) ? counts[t] : 0;
  s[t] = v;
  __syncthreads();
  for (int st = 1; st < 1024; st <<= 1) {
    int add = (t >= st) ? s[t - st] : 0;
    __syncthreads();
    s[t] += add;
    __syncthreads();
  }
  if (t < N) {
    offs[t + 1] = s[t];          // inclusive
    if (t == 0) offs[0] = 0;
    cursor[t] = s[t] - v;        // exclusive
  }
}

__global__ void k_fill(const int* __restrict__ ei, int* __restrict__ cursor,
                       int* __restrict__ csr_src, int* __restrict__ csr_eid) {
  int e = blockIdx.x * blockDim.x + threadIdx.x;
  if (e < E) {
    int src = ei[e];
    int dst = ei[E + e];
    int pos = atomicAdd(&cursor[dst], 1);
    csr_src[pos] = src;
    csr_eid[pos] = e;
  }
}

// ---------------- input projection ----------------
__global__ void k_inproj(const float* __restrict__ xw, const float* __restrict__ in_w,
                         const float* __restrict__ in_b, float* __restrict__ x) {
  __shared__ float xs[FIN];
  int r = blockIdx.x;
  int c = threadIdx.x;
  int b = r / RPB, rem = r % RPB;
  int wl = rem / N, n = rem % N;
  long gsrc = (((long)b * W + (W0G + wl)) * N + n) * FIN;
  if (c < FIN) xs[c] = xw[gsrc + c];
  __syncthreads();
  float acc = in_b[c];
  #pragma unroll
  for (int k = 0; k < FIN; k++) acc += xs[k] * in_w[k * H + c];
  x[(long)r * H + c] = acc;
}

// ---------------- FiLM (distinct rows only: E spatial + 1 temporal) ----------------
__global__ void k_film(const float* __restrict__ ea, const float* __restrict__ fw,
                       const float* __restrict__ fb, const float* __restrict__ meanea,
                       float* __restrict__ film) {
  int e = blockIdx.x;  // 0..E (E == temporal/mean row)
  int c = threadIdx.x; // 0..255
  __shared__ float a[DE];
  if (c < DE) a[c] = (e < E) ? ea[e * DE + c] : meanea[c];
  __syncthreads();
  float acc = fb[c];
  #pragma unroll
  for (int d = 0; d < DE; d++) acc += a[d] * fw[d * 2 * H + c];
  film[(long)e * 2 * H + c] = acc;
}

// ---------------- tiled GEMM: C = X @ W + b, 16 rows/block, 128 cols ----------------
__global__ void k_gemm(const float* __restrict__ X,
                       const float* __restrict__ Wq, const float* __restrict__ bq,
                       const float* __restrict__ Wk, const float* __restrict__ bk,
                       const float* __restrict__ Wv, const float* __restrict__ bv,
                       float* __restrict__ Cq, float* __restrict__ Ck, float* __restrict__ Cv,
                       int base, int tpb) {
  int m = blockIdx.y;
  const float* Wm = (m == 0) ? Wq : (m == 1) ? Wk : Wv;
  const float* bm = (m == 0) ? bq : (m == 1) ? bk : bv;
  float* Cm       = (m == 0) ? Cq : (m == 1) ? Ck : Cv;
  int bb = blockIdx.x / tpb;
  int t  = blockIdx.x % tpb;
  int lr0 = base + t * 16;
  int tid = threadIdx.x;
  __shared__ float xs[16][H];
  #pragma unroll
  for (int rr = 0; rr < 16; rr++) {
    int lr = lr0 + rr;
    if (lr < RPB) xs[rr][tid] = X[((long)bb * RPB + lr) * H + tid];
  }
  __syncthreads();
  float bc = bm[tid];
  float acc[16];
  #pragma unroll
  for (int r = 0; r < 16; r++) acc[r] = bc;
  #pragma unroll 4
  for (int k = 0; k < H; k++) {
    float w = Wm[k * H + tid];
    #pragma unroll
    for (int r = 0; r < 16; r++) acc[r] += xs[r][k] * w;
  }
  #pragma unroll
  for (int r = 0; r < 16; r++) {
    int lr = lr0 + r;
    if (lr < RPB) Cm[((long)bb * RPB + lr) * H + tid] = acc[r];
  }
}

// ---------------- attention (gather + online softmax; no atomics) ----------------
__global__ void k_attn(const float* __restrict__ Qb, const float* __restrict__ Kb,
                       const float* __restrict__ Vb, const float* __restrict__ film,
                       const int* __restrict__ offs, const int* __restrict__ csr_src,
                       const int* __restrict__ csr_eid, float* __restrict__ Ab,
                       int out_lo) {
  int nwin = WL - out_lo;
  int idx = blockIdx.x;
  int b = idx / (nwin * N);
  int rem = idx % (nwin * N);
  int wl = out_lo + rem / N;
  int n = rem % N;
  int tid = threadIdx.x;  // tid = h*32 + d
  long drow = ((long)b * WL + wl) * N + n;
  float q = Qb[drow * H + tid];
  long sbase = ((long)b * WL + wl) * N;       // spatial src rows (same window)
  long trow  = ((long)b * WL + wl - 1) * N + n;  // temporal src row
  const float scale = 0.17677669529663687f;   // 1/sqrt(32)
  float m = -INFINITY, ssum = 0.f, acc = 0.f;
  int i0 = offs[n], i1 = offs[n + 1];
  for (int i = i0; i <= i1; i++) {
    long srow; long fbase;
    if (i < i1) { srow = sbase + csr_src[i]; fbase = (long)csr_eid[i] * (2 * H); }
    else        { srow = trow;               fbase = (long)E * (2 * H); }
    float kv = Kb[srow * H + tid];
    float vv = Vb[srow * H + tid];
    float g  = film[fbase + tid];
    float be = film[fbase + H + tid];
    float p = q * (kv * (1.f + g) + be);
    // sum over the 32 lanes of this head (lanes of a head are contiguous)
    p += __shfl_xor(p, 16);
    p += __shfl_xor(p, 8);
    p += __shfl_xor(p, 4);
    p += __shfl_xor(p, 2);
    p += __shfl_xor(p, 1);
    float logit = p * scale;
    float mn = fmaxf(m, logit);
    float sc = expf(m - mn);       // first iter: exp(-inf)=0
    float pe = expf(logit - mn);
    ssum = ssum * sc + pe;
    acc  = acc * sc + pe * vv;
    m = mn;
  }
  Ab[drow * H + tid] = acc / (ssum + 1e-16f);
}

// ---------------- residual + layernorm ----------------
__global__ void k_ln(const float* __restrict__ x, const float* __restrict__ y,
                     const float* __restrict__ g, const float* __restrict__ bta,
                     float* __restrict__ xo, int out_lo) {
  int nwin = WL - out_lo;
  int idx = blockIdx.x;
  int b = idx / (nwin * N);
  int rem = idx % (nwin * N);
  int wl = out_lo + rem / N;
  int n = rem % N;
  long row = ((long)b * WL + wl) * N + n;
  int tid = threadIdx.x;
  float v = x[row * H + tid] + y[row * H + tid];
  float mu = blockSum128(v) * (1.f / H);
  float dv = v - mu;
  float var = blockSum128(dv * dv) * (1.f / H);
  float o = dv * rsqrtf(var + 1e-5f) * g[tid] + bta[tid];
  xo[row * H + tid] = o;
}

// ---------------- head ----------------
__global__ void k_head(const float* __restrict__ x, const float* __restrict__ hw,
                       const float* __restrict__ hb, float* __restrict__ out) {
  int idx = blockIdx.x;            // b*N + n
  int b = idx / N, n = idx % N;
  int tid = threadIdx.x;
  long row = ((long)b * WL + (WL - 1)) * N + n;  // last window
  float v = x[row * H + tid] * hw[tid];
  float tot = blockSum128(v);
  if (tid == 0) {
    float z = tot + hb[0];
    out[idx] = fmaxf(z, 0.f) + log1pf(expf(-fabsf(z)));  // softplus
  }
}

// ---------------- launch ----------------
extern "C" void kernel_launch(void* const* d_in, const int* in_sizes, int n_in,
                              void* d_out, int out_size, void* d_ws, size_t ws_size,
                              hipStream_t stream) {
  const float* xw   = (const float*)d_in[0];
  const int*   ei   = (const int*)d_in[1];
  const float* ea   = (const float*)d_in[2];
  const float* in_w = (const float*)d_in[3];
  const float* in_b = (const float*)d_in[4];
  const float* qw   = (const float*)d_in[5];
  const float* qb   = (const float*)d_in[6];
  const float* kw   = (const float*)d_in[7];
  const float* kb   = (const float*)d_in[8];
  const float* vw   = (const float*)d_in[9];
  const float* vb   = (const float*)d_in[10];
  const float* fw   = (const float*)d_in[11];
  const float* fb   = (const float*)d_in[12];
  const float* ow   = (const float*)d_in[13];
  const float* ob   = (const float*)d_in[14];
  const float* ln_g = (const float*)d_in[15];
  const float* ln_b = (const float*)d_in[16];
  const float* hw   = (const float*)d_in[17];
  const float* hb   = (const float*)d_in[18];
  float* out = (float*)d_out;

  // workspace carve-up
  float* ws   = (float*)d_ws;
  float* x    = ws;
  float* x2   = x  + (long)ROWS * H;
  float* Qb   = x2 + (long)ROWS * H;
  float* Kb   = Qb + (long)ROWS * H;
  float* Vb   = Kb + (long)ROWS * H;
  float* Ab   = Vb + (long)ROWS * H;
  float* Yb   = Ab + (long)ROWS * H;
  float* film = Yb + (long)ROWS * H;
  float* meanea = film + (long)(E + 1) * 2 * H;
  int* counts  = (int*)(meanea + 8);
  int* offs    = counts + N;
  int* cursor  = offs + N + 1;
  int* csr_src = cursor + N;
  int* csr_eid = csr_src + E;

  hipMemsetAsync(counts, 0, N * sizeof(int), stream);
  k_mean_ea<<<1, 256, 0, stream>>>(ea, meanea);
  k_count<<<(E + 255) / 256, 256, 0, stream>>>(ei, counts);
  k_scan<<<1, 1024, 0, stream>>>(counts, offs, cursor);
  k_fill<<<(E + 255) / 256, 256, 0, stream>>>(ei, cursor, csr_src, csr_eid);
  k_inproj<<<ROWS, 128, 0, stream>>>(xw, in_w, in_b, x);

  float* xa = x;
  float* xb = x2;
  for (int l = 0; l < L; l++) {
    int in_lo = l, out_lo = l + 1;
    k_film<<<E + 1, 2 * H, 0, stream>>>(ea, fw + (long)l * DE * 2 * H, fb + (long)l * 2 * H,
                                        meanea, film);
    int rows_pb = (WL - in_lo) * N;
    int tpb = (rows_pb + 15) / 16;
    k_gemm<<<dim3(B * tpb, 3), H, 0, stream>>>(
        xa, qw + (long)l * H * H, qb + (long)l * H, kw + (long)l * H * H, kb + (long)l * H,
        vw + (long)l * H * H, vb + (long)l * H, Qb, Kb, Vb, in_lo * N, tpb);
    int nout = B * (WL - out_lo) * N;
    k_attn<<<nout, H, 0, stream>>>(Qb, Kb, Vb, film, offs, csr_src, csr_eid, Ab, out_lo);
    int rows_pb2 = (WL - out_lo) * N;
    int tpb2 = (rows_pb2 + 15) / 16;
    k_gemm<<<dim3(B * tpb2, 1), H, 0, stream>>>(
        Ab, ow + (long)l * H * H, ob + (long)l * H, ow + (long)l * H * H, ob + (long)l * H,
        ow + (long)l * H * H, ob + (long)l * H, Yb, Yb, Yb, out_lo * N, tpb2);
    k_ln<<<nout, H, 0, stream>>>(xa, Yb, ln_g + (long)l * H, ln_b + (long)l * H, xb, out_lo);
    float* tmp = xa; xa = xb; xb = tmp;
  }
  k_head<<<B * N, H, 0, stream>>>(xa, hw, hb, out);
}

// Round 2
// 360.707 us; speedup vs baseline: 1.3184x; 1.3184x over previous
//
#include <hip/hip_runtime.h>
#include <math.h>

// Problem constants (fixed by setup_inputs)
constexpr int B    = 2;
constexpr int W    = 16;
constexpr int N    = 1000;
constexpr int FIN  = 16;
constexpr int E    = 16000;
constexpr int DE   = 8;
constexpr int H    = 128;   // hidden
constexpr int NH   = 4;     // heads
constexpr int DK   = 32;    // head dim
constexpr int L    = 3;
// Window pruning: only global windows 12..15 matter (temporal edges go t -> t+1,
// head reads only w=15, 3 layers => 3 hops back + input).
constexpr int WL   = 4;          // local windows kept (global 12..15)
constexpr int W0G  = 12;         // first kept global window
constexpr int RPB  = WL * N;     // rows per batch = 4000
constexpr int ROWS = B * RPB;    // 8000

// ---------------- helpers ----------------
__device__ __forceinline__ float blockSum128(float v) {
  #pragma unroll
  for (int off = 32; off >= 1; off >>= 1) v += __shfl_xor(v, off);
  __shared__ float s2[2];
  int w = threadIdx.x >> 6;
  __syncthreads();  // protect s2 reuse across multiple calls
  if ((threadIdx.x & 63) == 0) s2[w] = v;
  __syncthreads();
  return s2[0] + s2[1];
}

// ---------------- ea column-sum (parallel; result scaled by 1/E in k_film) ----------
__global__ void k_easum(const float* __restrict__ ea, float* __restrict__ easum) {
  __shared__ float sbuf[256];
  int t = threadIdx.x;
  int d = t & 7, g = t >> 3;  // 32 row-groups x 8 attrs per block
  float s = 0.f;
  for (int e = blockIdx.x * 32 + g; e < E; e += gridDim.x * 32) s += ea[e * DE + d];
  sbuf[t] = s;
  __syncthreads();
  for (int st = 16; st >= 1; st >>= 1) {
    if (g < st) sbuf[g * 8 + d] += sbuf[(g + st) * 8 + d];
    __syncthreads();
  }
  if (g == 0) atomicAdd(&easum[d], sbuf[d]);
}

// ---------------- graph prep ----------------
__global__ void k_count(const int* __restrict__ ei, int* __restrict__ counts) {
  int e = blockIdx.x * blockDim.x + threadIdx.x;
  if (e < E) atomicAdd(&counts[ei[E + e]], 1);
}

__global__ void k_scan(const int* __restrict__ counts, int* __restrict__ offs,
                       int* __restrict__ cursor) {
  __shared__ int s[1024];
  int t = threadIdx.x;
  int v = (t < N) ? counts[t] : 0;
  s[t] = v;
  __syncthreads();
  for (int st = 1; st < 1024; st <<= 1) {
    int add = (t >= st) ? s[t - st] : 0;
    __syncthreads();
    s[t] += add;
    __syncthreads();
  }
  if (t < N) {
    offs[t + 1] = s[t];          // inclusive
    if (t == 0) offs[0] = 0;
    cursor[t] = s[t] - v;        // exclusive
  }
}

__global__ void k_fill(const int* __restrict__ ei, int* __restrict__ cursor,
                       int* __restrict__ csr_src, int* __restrict__ csr_eid) {
  int e = blockIdx.x * blockDim.x + threadIdx.x;
  if (e < E) {
    int src = ei[e];
    int dst = ei[E + e];
    int pos = atomicAdd(&cursor[dst], 1);
    csr_src[pos] = src;
    csr_eid[pos] = e;
  }
}

// ---------------- input projection ----------------
__global__ void k_inproj(const float* __restrict__ xw, const float* __restrict__ in_w,
                         const float* __restrict__ in_b, float* __restrict__ x) {
  __shared__ float xs[FIN];
  int r = blockIdx.x;
  int c = threadIdx.x;
  int b = r / RPB, rem = r % RPB;
  int wl = rem / N, n = rem % N;
  long gsrc = (((long)b * W + (W0G + wl)) * N + n) * FIN;
  if (c < FIN) xs[c] = xw[gsrc + c];
  __syncthreads();
  float acc = in_b[c];
  #pragma unroll
  for (int k = 0; k < FIN; k++) acc += xs[k] * in_w[k * H + c];
  x[(long)r * H + c] = acc;
}

// ---------------- FiLM (distinct rows only: E spatial + 1 temporal) ----------------
__global__ void k_film(const float* __restrict__ ea, const float* __restrict__ fw,
                       const float* __restrict__ fb, const float* __restrict__ easum,
                       float* __restrict__ film) {
  int e = blockIdx.x;  // 0..E (E == temporal/mean row)
  int c = threadIdx.x; // 0..255
  __shared__ float a[DE];
  if (c < DE) a[c] = (e < E) ? ea[e * DE + c] : easum[c] * (1.0f / E);
  __syncthreads();
  float acc = fb[c];
  #pragma unroll
  for (int d = 0; d < DE; d++) acc += a[d] * fw[d * 2 * H + c];
  film[(long)e * 2 * H + c] = acc;
}

// ---------------- tiled GEMM: C = X @ W + b, 16 rows/block, 128 cols ----------------
__global__ void k_gemm(const float* __restrict__ X,
                       const float* __restrict__ Wq, const float* __restrict__ bq,
                       const float* __restrict__ Wk, const float* __restrict__ bk,
                       const float* __restrict__ Wv, const float* __restrict__ bv,
                       float* __restrict__ Cq, float* __restrict__ Ck, float* __restrict__ Cv,
                       int base, int tpb) {
  int m = blockIdx.y;
  const float* Wm = (m == 0) ? Wq : (m == 1) ? Wk : Wv;
  const float* bm = (m == 0) ? bq : (m == 1) ? bk : bv;
  float* Cm       = (m == 0) ? Cq : (m == 1) ? Ck : Cv;
  int bb = blockIdx.x / tpb;
  int t  = blockIdx.x % tpb;
  int lr0 = base + t * 16;
  int tid = threadIdx.x;
  __shared__ float xs[16][H];
  #pragma unroll
  for (int rr = 0; rr < 16; rr++) {
    int lr = lr0 + rr;
    if (lr < RPB) xs[rr][tid] = X[((long)bb * RPB + lr) * H + tid];
  }
  __syncthreads();
  float bc = bm[tid];
  float acc[16];
  #pragma unroll
  for (int r = 0; r < 16; r++) acc[r] = bc;
  #pragma unroll 4
  for (int k = 0; k < H; k++) {
    float w = Wm[k * H + tid];
    #pragma unroll
    for (int r = 0; r < 16; r++) acc[r] += xs[r][k] * w;
  }
  #pragma unroll
  for (int r = 0; r < 16; r++) {
    int lr = lr0 + r;
    if (lr < RPB) Cm[((long)bb * RPB + lr) * H + tid] = acc[r];
  }
}

// ---------------- attention (gather + online softmax; no atomics) ----------------
__global__ void k_attn(const float* __restrict__ Qb, const float* __restrict__ Kb,
                       const float* __restrict__ Vb, const float* __restrict__ film,
                       const int* __restrict__ offs, const int* __restrict__ csr_src,
                       const int* __restrict__ csr_eid, float* __restrict__ Ab,
                       int out_lo) {
  int nwin = WL - out_lo;
  int idx = blockIdx.x;
  int b = idx / (nwin * N);
  int rem = idx % (nwin * N);
  int wl = out_lo + rem / N;
  int n = rem % N;
  int tid = threadIdx.x;  // tid = h*32 + d
  long drow = ((long)b * WL + wl) * N + n;
  float q = Qb[drow * H + tid];
  long sbase = ((long)b * WL + wl) * N;       // spatial src rows (same window)
  long trow  = ((long)b * WL + wl - 1) * N + n;  // temporal src row
  const float scale = 0.17677669529663687f;   // 1/sqrt(32)
  float m = -INFINITY, ssum = 0.f, acc = 0.f;
  int i0 = offs[n], i1 = offs[n + 1];
  for (int i = i0; i <= i1; i++) {
    long srow; long fbase;
    if (i < i1) { srow = sbase + csr_src[i]; fbase = (long)csr_eid[i] * (2 * H); }
    else        { srow = trow;               fbase = (long)E * (2 * H); }
    float kv = Kb[srow * H + tid];
    float vv = Vb[srow * H + tid];
    float g  = film[fbase + tid];
    float be = film[fbase + H + tid];
    float p = q * (kv * (1.f + g) + be);
    // sum over the 32 lanes of this head (lanes of a head are contiguous)
    p += __shfl_xor(p, 16);
    p += __shfl_xor(p, 8);
    p += __shfl_xor(p, 4);
    p += __shfl_xor(p, 2);
    p += __shfl_xor(p, 1);
    float logit = p * scale;
    float mn = fmaxf(m, logit);
    float sc = expf(m - mn);       // first iter: exp(-inf)=0
    float pe = expf(logit - mn);
    ssum = ssum * sc + pe;
    acc  = acc * sc + pe * vv;
    m = mn;
  }
  Ab[drow * H + tid] = acc / (ssum + 1e-16f);
}

// ---------------- residual + layernorm ----------------
__global__ void k_ln(const float* __restrict__ x, const float* __restrict__ y,
                     const float* __restrict__ g, const float* __restrict__ bta,
                     float* __restrict__ xo, int out_lo) {
  int nwin = WL - out_lo;
  int idx = blockIdx.x;
  int b = idx / (nwin * N);
  int rem = idx % (nwin * N);
  int wl = out_lo + rem / N;
  int n = rem % N;
  long row = ((long)b * WL + wl) * N + n;
  int tid = threadIdx.x;
  float v = x[row * H + tid] + y[row * H + tid];
  float mu = blockSum128(v) * (1.f / H);
  float dv = v - mu;
  float var = blockSum128(dv * dv) * (1.f / H);
  float o = dv * rsqrtf(var + 1e-5f) * g[tid] + bta[tid];
  xo[row * H + tid] = o;
}

// ---------------- head ----------------
__global__ void k_head(const float* __restrict__ x, const float* __restrict__ hw,
                       const float* __restrict__ hb, float* __restrict__ out) {
  int idx = blockIdx.x;            // b*N + n
  int b = idx / N, n = idx % N;
  int tid = threadIdx.x;
  long row = ((long)b * WL + (WL - 1)) * N + n;  // last window
  float v = x[row * H + tid] * hw[tid];
  float tot = blockSum128(v);
  if (tid == 0) {
    float z = tot + hb[0];
    out[idx] = fmaxf(z, 0.f) + log1pf(expf(-fabsf(z)));  // softplus
  }
}

// ---------------- launch ----------------
extern "C" void kernel_launch(void* const* d_in, const int* in_sizes, int n_in,
                              void* d_out, int out_size, void* d_ws, size_t ws_size,
                              hipStream_t stream) {
  const float* xw   = (const float*)d_in[0];
  const int*   ei   = (const int*)d_in[1];
  const float* ea   = (const float*)d_in[2];
  const float* in_w = (const float*)d_in[3];
  const float* in_b = (const float*)d_in[4];
  const float* qw   = (const float*)d_in[5];
  const float* qb   = (const float*)d_in[6];
  const float* kw   = (const float*)d_in[7];
  const float* kb   = (const float*)d_in[8];
  const float* vw   = (const float*)d_in[9];
  const float* vb   = (const float*)d_in[10];
  const float* fw   = (const float*)d_in[11];
  const float* fb   = (const float*)d_in[12];
  const float* ow   = (const float*)d_in[13];
  const float* ob   = (const float*)d_in[14];
  const float* ln_g = (const float*)d_in[15];
  const float* ln_b = (const float*)d_in[16];
  const float* hw   = (const float*)d_in[17];
  const float* hb   = (const float*)d_in[18];
  float* out = (float*)d_out;

  // workspace carve-up
  float* ws   = (float*)d_ws;
  float* x    = ws;
  float* x2   = x  + (long)ROWS * H;
  float* Qb   = x2 + (long)ROWS * H;
  float* Kb   = Qb + (long)ROWS * H;
  float* Vb   = Kb + (long)ROWS * H;
  float* Ab   = Vb + (long)ROWS * H;
  float* Yb   = Ab + (long)ROWS * H;
  float* film = Yb + (long)ROWS * H;
  float* easum = film + (long)(E + 1) * 2 * H;   // 8 floats, zeroed below
  int* counts  = (int*)(easum + 8);              // N ints, zeroed below
  int* offs    = counts + N;
  int* cursor  = offs + N + 1;
  int* csr_src = cursor + N;
  int* csr_eid = csr_src + E;

  // zero easum (8 floats) + counts (N ints) in one contiguous memset
  hipMemsetAsync(easum, 0, 8 * sizeof(float) + N * sizeof(int), stream);
  k_easum<<<64, 256, 0, stream>>>(ea, easum);
  k_count<<<(E + 255) / 256, 256, 0, stream>>>(ei, counts);
  k_scan<<<1, 1024, 0, stream>>>(counts, offs, cursor);
  k_fill<<<(E + 255) / 256, 256, 0, stream>>>(ei, cursor, csr_src, csr_eid);
  k_inproj<<<ROWS, 128, 0, stream>>>(xw, in_w, in_b, x);

  float* xa = x;
  float* xb = x2;
  for (int l = 0; l < L; l++) {
    int in_lo = l, out_lo = l + 1;
    k_film<<<E + 1, 2 * H, 0, stream>>>(ea, fw + (long)l * DE * 2 * H, fb + (long)l * 2 * H,
                                        easum, film);
    int rows_pb = (WL - in_lo) * N;
    int tpb = (rows_pb + 15) / 16;
    k_gemm<<<dim3(B * tpb, 3), H, 0, stream>>>(
        xa, qw + (long)l * H * H, qb + (long)l * H, kw + (long)l * H * H, kb + (long)l * H,
        vw + (long)l * H * H, vb + (long)l * H, Qb, Kb, Vb, in_lo * N, tpb);
    int nout = B * (WL - out_lo) * N;
    k_attn<<<nout, H, 0, stream>>>(Qb, Kb, Vb, film, offs, csr_src, csr_eid, Ab, out_lo);
    int rows_pb2 = (WL - out_lo) * N;
    int tpb2 = (rows_pb2 + 15) / 16;
    k_gemm<<<dim3(B * tpb2, 1), H, 0, stream>>>(
        Ab, ow + (long)l * H * H, ob + (long)l * H, ow + (long)l * H * H, ob + (long)l * H,
        ow + (long)l * H * H, ob + (long)l * H, Yb, Yb, Yb, out_lo * N, tpb2);
    k_ln<<<nout, H, 0, stream>>>(xa, Yb, ln_g + (long)l * H, ln_b + (long)l * H, xb, out_lo);
    float* tmp = xa; xa = xb; xb = tmp;
  }
  k_head<<<B * N, H, 0, stream>>>(xa, hw, hb, out);
}

// Round 3
// 311.226 us; speedup vs baseline: 1.5280x; 1.1590x over previous
//
#include <hip/hip_runtime.h>
#include <math.h>

// Problem constants (fixed by setup_inputs)
constexpr int B    = 2;
constexpr int W    = 16;
constexpr int N    = 1000;
constexpr int FIN  = 16;
constexpr int E    = 16000;
constexpr int DE   = 8;
constexpr int H    = 128;   // hidden
constexpr int L    = 3;
// Window pruning: temporal edges go t -> t+1 and head reads only w=15;
// 3 layers => only global windows 12..15 matter.
constexpr int WL   = 4;          // local windows kept (global 12..15)
constexpr int W0G  = 12;         // first kept global window
constexpr int RPB  = WL * N;     // rows per batch = 4000
constexpr int ROWS = B * RPB;    // 8000
constexpr int EASUM_BLOCKS = 64;

// ---------------- helpers ----------------
__device__ __forceinline__ float blockSum128(float v) {
  #pragma unroll
  for (int off = 32; off >= 1; off >>= 1) v += __shfl_xor(v, off);
  __shared__ float s2[2];
  int w = threadIdx.x >> 6;
  __syncthreads();  // protect s2 reuse across multiple calls
  if ((threadIdx.x & 63) == 0) s2[w] = v;
  __syncthreads();
  return s2[0] + s2[1];
}

// ---------------- ea column partial sums (no memset, no atomics) ----------------
__global__ void k_easum(const float* __restrict__ ea, float* __restrict__ part) {
  __shared__ float sbuf[256];
  int t = threadIdx.x;
  int d = t & 7, g = t >> 3;  // 32 row-groups x 8 attrs per block
  float s = 0.f;
  for (int e = blockIdx.x * 32 + g; e < E; e += EASUM_BLOCKS * 32) s += ea[e * DE + d];
  sbuf[t] = s;
  __syncthreads();
  for (int st = 16; st >= 1; st >>= 1) {
    if (g < st) sbuf[g * 8 + d] += sbuf[(g + st) * 8 + d];
    __syncthreads();
  }
  if (g == 0) part[blockIdx.x * 8 + d] = sbuf[d];
}

// ---------------- graph build: count + scan + fill, one block, all in LDS ------
__global__ void k_graph(const int* __restrict__ ei, int* __restrict__ offs,
                        int* __restrict__ csr_src, int* __restrict__ csr_eid) {
  __shared__ int cnt[N];
  __shared__ int scn[1024];
  __shared__ int cur[N];
  int t = threadIdx.x;  // 0..1023
  if (t < N) cnt[t] = 0;
  __syncthreads();
  for (int e = t; e < E; e += 1024) atomicAdd(&cnt[ei[E + e]], 1);
  __syncthreads();
  int v = (t < N) ? cnt[t] : 0;
  scn[t] = v;
  __syncthreads();
  for (int st = 1; st < 1024; st <<= 1) {
    int add = (t >= st) ? scn[t - st] : 0;
    __syncthreads();
    scn[t] += add;
    __syncthreads();
  }
  if (t < N) {
    offs[t + 1] = scn[t];
    if (t == 0) offs[0] = 0;
    cur[t] = scn[t] - v;
  }
  __syncthreads();
  for (int e = t; e < E; e += 1024) {
    int src = ei[e];
    int dst = ei[E + e];
    int pos = atomicAdd(&cur[dst], 1);
    csr_src[pos] = src;
    csr_eid[pos] = e;
  }
}

// ---------------- FiLM for ALL layers (E spatial rows + 1 temporal row) --------
__global__ void k_film_all(const float* __restrict__ ea, const float* __restrict__ fw,
                           const float* __restrict__ fb, const float* __restrict__ part,
                           float* __restrict__ filmAll) {
  int l = blockIdx.y;
  int e = blockIdx.x;  // 0..E (E == temporal/mean row)
  int c = threadIdx.x; // 0..255
  __shared__ float a[DE];
  if (e < E) {
    if (c < DE) a[c] = ea[e * DE + c];
  } else {
    __shared__ float sbuf[256];
    int d = c & 7, g = c >> 3;
    float s = 0.f;
    for (int p = g; p < EASUM_BLOCKS; p += 32) s += part[p * 8 + d];
    sbuf[c] = s;
    __syncthreads();
    for (int st = 16; st >= 1; st >>= 1) {
      if (g < st) sbuf[g * 8 + d] += sbuf[(g + st) * 8 + d];
      __syncthreads();
    }
    if (g == 0) a[d] = sbuf[d] * (1.0f / E);
  }
  __syncthreads();
  const float* fwl = fw + (long)l * DE * 2 * H;
  float acc = fb[(long)l * 2 * H + c];
  #pragma unroll
  for (int d = 0; d < DE; d++) acc += a[d] * fwl[d * 2 * H + c];
  filmAll[((long)l * (E + 1) + e) * 2 * H + c] = acc;
}

// ---------------- tiled GEMM: QKV = X @ W + b, 16 rows/block, 128 cols ---------
// fuse_in: compute X-tile on the fly from xw @ in_w + in_b (layer 0);
//          m==0 block also materializes x for the residual path.
__global__ void k_gemm(const float* __restrict__ X, const float* __restrict__ xw,
                       const float* __restrict__ in_w, const float* __restrict__ in_b,
                       const float* __restrict__ Wq, const float* __restrict__ bq,
                       const float* __restrict__ Wk, const float* __restrict__ bk,
                       const float* __restrict__ Wv, const float* __restrict__ bv,
                       float* __restrict__ Cq, float* __restrict__ Ck, float* __restrict__ Cv,
                       float* __restrict__ xout,
                       int base, int tpb, int fuse_in) {
  int m = blockIdx.y;
  const float* Wm = (m == 0) ? Wq : (m == 1) ? Wk : Wv;
  const float* bm = (m == 0) ? bq : (m == 1) ? bk : bv;
  float* Cm       = (m == 0) ? Cq : (m == 1) ? Ck : Cv;
  int bb = blockIdx.x / tpb;
  int t  = blockIdx.x % tpb;
  int lr0 = base + t * 16;
  int tid = threadIdx.x;
  __shared__ float xs[16][H];
  if (fuse_in) {
    __shared__ float xws[16][FIN];
    for (int i = tid; i < 16 * FIN; i += 128) {
      int rr = i >> 4, k = i & 15;
      int lr = lr0 + rr;
      if (lr < RPB) {
        int wl = lr / N, n = lr % N;
        xws[rr][k] = xw[(((long)bb * W + (W0G + wl)) * N + n) * FIN + k];
      }
    }
    __syncthreads();
    float bc = in_b[tid];
    #pragma unroll
    for (int rr = 0; rr < 16; rr++) {
      float acc = bc;
      #pragma unroll
      for (int k = 0; k < FIN; k++) acc += xws[rr][k] * in_w[k * H + tid];
      xs[rr][tid] = acc;
      int lr = lr0 + rr;
      if (m == 0 && lr < RPB) xout[((long)bb * RPB + lr) * H + tid] = acc;
    }
  } else {
    #pragma unroll
    for (int rr = 0; rr < 16; rr++) {
      int lr = lr0 + rr;
      if (lr < RPB) xs[rr][tid] = X[((long)bb * RPB + lr) * H + tid];
    }
  }
  __syncthreads();
  float bc = bm[tid];
  float acc[16];
  #pragma unroll
  for (int r = 0; r < 16; r++) acc[r] = bc;
  #pragma unroll 4
  for (int k = 0; k < H; k++) {
    float w = Wm[k * H + tid];
    #pragma unroll
    for (int r = 0; r < 16; r++) acc[r] += xs[r][k] * w;
  }
  #pragma unroll
  for (int r = 0; r < 16; r++) {
    int lr = lr0 + r;
    if (lr < RPB) Cm[((long)bb * RPB + lr) * H + tid] = acc[r];
  }
}

// ------- fused: attention (gather, online softmax) + O-proj + residual + LN ----
// Optionally fuses the softplus head (last layer) and skips writing x.
__global__ void k_attn_oln(const float* __restrict__ Qb, const float* __restrict__ Kb,
                           const float* __restrict__ Vb, const float* __restrict__ film,
                           const int* __restrict__ offs, const int* __restrict__ csr_src,
                           const int* __restrict__ csr_eid,
                           const float* __restrict__ x, const float* __restrict__ ow,
                           const float* __restrict__ ob, const float* __restrict__ lng,
                           const float* __restrict__ lnb, float* __restrict__ xo,
                           int out_lo,
                           const float* __restrict__ hw, const float* __restrict__ hb,
                           float* __restrict__ out, int do_head) {
  int nwin = WL - out_lo;
  int idx = blockIdx.x;
  int b = idx / (nwin * N);
  int rem = idx % (nwin * N);
  int wl = out_lo + rem / N;
  int n = rem % N;
  int tid = threadIdx.x;  // tid = h*32 + d
  long drow = ((long)b * WL + wl) * N + n;
  float q = Qb[drow * H + tid];
  long sbase = ((long)b * WL + wl) * N;          // spatial src rows (same window)
  long trow  = ((long)b * WL + wl - 1) * N + n;  // temporal src row
  const float scale = 0.17677669529663687f;      // 1/sqrt(32)
  float m = -INFINITY, ssum = 0.f, acc = 0.f;
  int i0 = offs[n], i1 = offs[n + 1];
  for (int i = i0; i <= i1; i++) {
    long srow; long fbase;
    if (i < i1) { srow = sbase + csr_src[i]; fbase = (long)csr_eid[i] * (2 * H); }
    else        { srow = trow;               fbase = (long)E * (2 * H); }
    float kv = Kb[srow * H + tid];
    float vv = Vb[srow * H + tid];
    float g  = film[fbase + tid];
    float be = film[fbase + H + tid];
    float p = q * (kv * (1.f + g) + be);
    // sum over the 32 lanes of this head (head lanes are contiguous)
    p += __shfl_xor(p, 16);
    p += __shfl_xor(p, 8);
    p += __shfl_xor(p, 4);
    p += __shfl_xor(p, 2);
    p += __shfl_xor(p, 1);
    float logit = p * scale;
    float mn = fmaxf(m, logit);
    float sc = expf(m - mn);       // first iter: exp(-inf)=0
    float pe = expf(logit - mn);
    ssum = ssum * sc + pe;
    acc  = acc * sc + pe * vv;
    m = mn;
  }
  float ab = acc / (ssum + 1e-16f);

  // ---- O-projection: y[c] = ob[c] + sum_k ab[k] * ow[k][c] ----
  __shared__ float sab[H];
  sab[tid] = ab;
  __syncthreads();
  float y = ob[tid];
  #pragma unroll 8
  for (int k = 0; k < H; k++) y += sab[k] * ow[k * H + tid];

  // ---- residual + layernorm ----
  float v = x[drow * H + tid] + y;
  float mu = blockSum128(v) * (1.f / H);
  float dv = v - mu;
  float var = blockSum128(dv * dv) * (1.f / H);
  float o = dv * rsqrtf(var + 1e-5f) * lng[tid] + lnb[tid];

  if (!do_head) {
    xo[drow * H + tid] = o;
  } else {
    float hv = o * hw[tid];
    float tot = blockSum128(hv);
    if (tid == 0) {
      float z = tot + hb[0];
      out[b * N + n] = fmaxf(z, 0.f) + log1pf(expf(-fabsf(z)));  // softplus
    }
  }
}

// ---------------- launch ----------------
extern "C" void kernel_launch(void* const* d_in, const int* in_sizes, int n_in,
                              void* d_out, int out_size, void* d_ws, size_t ws_size,
                              hipStream_t stream) {
  const float* xw   = (const float*)d_in[0];
  const int*   ei   = (const int*)d_in[1];
  const float* ea   = (const float*)d_in[2];
  const float* in_w = (const float*)d_in[3];
  const float* in_b = (const float*)d_in[4];
  const float* qw   = (const float*)d_in[5];
  const float* qb   = (const float*)d_in[6];
  const float* kw   = (const float*)d_in[7];
  const float* kb   = (const float*)d_in[8];
  const float* vw   = (const float*)d_in[9];
  const float* vb   = (const float*)d_in[10];
  const float* fw   = (const float*)d_in[11];
  const float* fb   = (const float*)d_in[12];
  const float* ow   = (const float*)d_in[13];
  const float* ob   = (const float*)d_in[14];
  const float* ln_g = (const float*)d_in[15];
  const float* ln_b = (const float*)d_in[16];
  const float* hw   = (const float*)d_in[17];
  const float* hb   = (const float*)d_in[18];
  float* out = (float*)d_out;

  // workspace carve-up
  float* ws   = (float*)d_ws;
  float* x    = ws;
  float* x2   = x  + (long)ROWS * H;
  float* Qb   = x2 + (long)ROWS * H;
  float* Kb   = Qb + (long)ROWS * H;
  float* Vb   = Kb + (long)ROWS * H;
  float* filmAll = Vb + (long)ROWS * H;                 // 3 layers x (E+1) x 2H
  float* part    = filmAll + (long)L * (E + 1) * 2 * H; // 64*8 partials
  int* offs    = (int*)(part + EASUM_BLOCKS * 8);
  int* csr_src = offs + N + 1;
  int* csr_eid = csr_src + E;

  k_easum<<<EASUM_BLOCKS, 256, 0, stream>>>(ea, part);
  k_graph<<<1, 1024, 0, stream>>>(ei, offs, csr_src, csr_eid);
  k_film_all<<<dim3(E + 1, L), 2 * H, 0, stream>>>(ea, fw, fb, part, filmAll);

  float* xa = x;
  float* xb = x2;
  for (int l = 0; l < L; l++) {
    int in_lo = l, out_lo = l + 1;
    int rows_pb = (WL - in_lo) * N;
    int tpb = (rows_pb + 15) / 16;
    k_gemm<<<dim3(B * tpb, 3), H, 0, stream>>>(
        xa, xw, in_w, in_b,
        qw + (long)l * H * H, qb + (long)l * H, kw + (long)l * H * H, kb + (long)l * H,
        vw + (long)l * H * H, vb + (long)l * H, Qb, Kb, Vb, xa,
        in_lo * N, tpb, (l == 0) ? 1 : 0);
    int nout = B * (WL - out_lo) * N;
    int last = (l == L - 1) ? 1 : 0;
    k_attn_oln<<<nout, H, 0, stream>>>(
        Qb, Kb, Vb, filmAll + (long)l * (E + 1) * 2 * H, offs, csr_src, csr_eid,
        xa, ow + (long)l * H * H, ob + (long)l * H,
        ln_g + (long)l * H, ln_b + (long)l * H, xb, out_lo,
        hw, hb, out, last);
    float* tmp = xa; xa = xb; xb = tmp;
  }
}

// Round 4
// 288.822 us; speedup vs baseline: 1.6466x; 1.0776x over previous
//
#include <hip/hip_runtime.h>
#include <math.h>

// Problem constants (fixed by setup_inputs)
constexpr int B    = 2;
constexpr int W    = 16;
constexpr int N    = 1000;
constexpr int FIN  = 16;
constexpr int E    = 16000;
constexpr int DE   = 8;
constexpr int H    = 128;   // hidden
constexpr int L    = 3;
// Window pruning: temporal edges go t -> t+1 and head reads only w=15;
// 3 layers => only global windows 12..15 matter.
constexpr int WL   = 4;          // local windows kept (global 12..15)
constexpr int W0G  = 12;         // first kept global window
constexpr int RPB  = WL * N;     // rows per batch = 4000
constexpr int ROWS = B * RPB;    // 8000

// ---------------- helpers ----------------
__device__ __forceinline__ float blockSum128(float v) {
  #pragma unroll
  for (int off = 32; off >= 1; off >>= 1) v += __shfl_xor(v, off);
  __shared__ float s2[2];
  int w = threadIdx.x >> 6;
  __syncthreads();  // protect s2 reuse across multiple calls
  if ((threadIdx.x & 63) == 0) s2[w] = v;
  __syncthreads();
  return s2[0] + s2[1];
}

// ------- graph count+scan (1 block; reads only dst row, prefetched) -------
__global__ void k_count_scan(const int* __restrict__ ei, int* __restrict__ offs,
                             int* __restrict__ cursor, float* __restrict__ meanea) {
  __shared__ int cnt[N];
  __shared__ int scn[1024];
  int t = threadIdx.x;  // 0..1023
  if (t < 8) meanea[t] = 0.f;     // zero accumulator for k_prep2's atomics
  if (t < N) cnt[t] = 0;
  __syncthreads();
  // prefetch all dst indices (<=16 per thread), then LDS atomics
  int vals[16];
  int nv = 0;
  for (int e = t; e < E; e += 1024) vals[nv++] = ei[E + e];
  for (int i = 0; i < nv; i++) atomicAdd(&cnt[vals[i]], 1);
  __syncthreads();
  int v = (t < N) ? cnt[t] : 0;
  scn[t] = v;
  __syncthreads();
  for (int st = 1; st < 1024; st <<= 1) {
    int add = (t >= st) ? scn[t - st] : 0;
    __syncthreads();
    scn[t] += add;
    __syncthreads();
  }
  if (t < N) {
    offs[t + 1] = scn[t];
    if (t == 0) offs[0] = 0;
    cursor[t] = scn[t] - v;
  }
}

// ------- CSR fill (blocks 0..63) + ea column-sum (blocks 64..127) -------
__global__ void k_prep2(const int* __restrict__ ei, const float* __restrict__ ea,
                        int* __restrict__ cursor, int* __restrict__ csr_src,
                        int* __restrict__ csr_eid, float* __restrict__ meanea) {
  int bid = blockIdx.x;
  int t = threadIdx.x;  // 256 threads
  if (bid < 64) {
    int e = bid * 256 + t;
    if (e < E) {
      int src = ei[e];
      int dst = ei[E + e];
      int pos = atomicAdd(&cursor[dst], 1);
      csr_src[pos] = src;
      csr_eid[pos] = e;
    }
  } else {
    __shared__ float sbuf[256];
    int d = t & 7, g = t >> 3;  // 32 row-groups x 8 attrs
    float s = 0.f;
    for (int e = (bid - 64) * 32 + g; e < E; e += 64 * 32) s += ea[e * DE + d];
    sbuf[t] = s;
    __syncthreads();
    for (int st = 16; st >= 1; st >>= 1) {
      if (g < st) sbuf[g * 8 + d] += sbuf[(g + st) * 8 + d];
      __syncthreads();
    }
    if (g == 0) atomicAdd(&meanea[d], sbuf[d]);
  }
}

// ---------------- tiled GEMM: QKV = X @ W + b, 16 rows/block, 128 cols ---------
// fuse_in: compute X-tile on the fly from xw @ in_w + in_b (layer 0);
//          m==0 block also materializes x for the residual path.
__global__ void k_gemm(const float* __restrict__ X, const float* __restrict__ xw,
                       const float* __restrict__ in_w, const float* __restrict__ in_b,
                       const float* __restrict__ Wq, const float* __restrict__ bq,
                       const float* __restrict__ Wk, const float* __restrict__ bk,
                       const float* __restrict__ Wv, const float* __restrict__ bv,
                       float* __restrict__ Cq, float* __restrict__ Ck, float* __restrict__ Cv,
                       float* __restrict__ xout,
                       int base, int tpb, int fuse_in) {
  int m = blockIdx.y;
  const float* Wm = (m == 0) ? Wq : (m == 1) ? Wk : Wv;
  const float* bm = (m == 0) ? bq : (m == 1) ? bk : bv;
  float* Cm       = (m == 0) ? Cq : (m == 1) ? Ck : Cv;
  int bb = blockIdx.x / tpb;
  int t  = blockIdx.x % tpb;
  int lr0 = base + t * 16;
  int tid = threadIdx.x;
  __shared__ float xs[16][H];
  if (fuse_in) {
    __shared__ float xws[16][FIN];
    for (int i = tid; i < 16 * FIN; i += 128) {
      int rr = i >> 4, k = i & 15;
      int lr = lr0 + rr;
      if (lr < RPB) {
        int wl = lr / N, n = lr % N;
        xws[rr][k] = xw[(((long)bb * W + (W0G + wl)) * N + n) * FIN + k];
      }
    }
    __syncthreads();
    float bc = in_b[tid];
    #pragma unroll
    for (int rr = 0; rr < 16; rr++) {
      float acc = bc;
      #pragma unroll
      for (int k = 0; k < FIN; k++) acc += xws[rr][k] * in_w[k * H + tid];
      xs[rr][tid] = acc;
      int lr = lr0 + rr;
      if (m == 0 && lr < RPB) xout[((long)bb * RPB + lr) * H + tid] = acc;
    }
  } else {
    #pragma unroll
    for (int rr = 0; rr < 16; rr++) {
      int lr = lr0 + rr;
      if (lr < RPB) xs[rr][tid] = X[((long)bb * RPB + lr) * H + tid];
    }
  }
  __syncthreads();
  float bc = bm[tid];
  float acc[16];
  #pragma unroll
  for (int r = 0; r < 16; r++) acc[r] = bc;
  #pragma unroll 4
  for (int k = 0; k < H; k++) {
    float w = Wm[k * H + tid];
    #pragma unroll
    for (int r = 0; r < 16; r++) acc[r] += xs[r][k] * w;
  }
  #pragma unroll
  for (int r = 0; r < 16; r++) {
    int lr = lr0 + r;
    if (lr < RPB) Cm[((long)bb * RPB + lr) * H + tid] = acc[r];
  }
}

// ------- fused: attention (gather, online softmax, on-the-fly FiLM, 4-edge ILP)
//         + O-proj + residual + LN (+ optional softplus head) -------
__global__ void k_attn_oln(const float* __restrict__ Qb, const float* __restrict__ Kb,
                           const float* __restrict__ Vb,
                           const float* __restrict__ ea, const float* __restrict__ meanea,
                           const float* __restrict__ fw, const float* __restrict__ fb,
                           const int* __restrict__ offs, const int* __restrict__ csr_src,
                           const int* __restrict__ csr_eid,
                           const float* __restrict__ x, const float* __restrict__ ow,
                           const float* __restrict__ ob, const float* __restrict__ lng,
                           const float* __restrict__ lnb, float* __restrict__ xo,
                           int out_lo,
                           const float* __restrict__ hw, const float* __restrict__ hb,
                           float* __restrict__ out, int do_head) {
  __shared__ float fwS[DE][2 * H];  // 8 KB: FiLM weight slice for this layer
  int tid = threadIdx.x;  // tid = h*32 + d
  for (int i = tid; i < DE * 2 * H; i += H) fwS[i >> 8][i & 255] = fw[i];

  int nwin = WL - out_lo;
  int idx = blockIdx.x;
  int b = idx / (nwin * N);
  int rem = idx % (nwin * N);
  int wl = out_lo + rem / N;
  int n = rem % N;
  long drow = ((long)b * WL + wl) * N + n;
  float q = Qb[drow * H + tid];
  float fbg = fb[tid], fbb = fb[H + tid];
  long sbase = ((long)b * WL + wl) * N;          // spatial src rows (same window)
  long trow  = ((long)b * WL + wl - 1) * N + n;  // temporal src row
  const float scale = 0.17677669529663687f;      // 1/sqrt(32)
  int i0 = offs[n], i1 = offs[n + 1];            // edge i1 == temporal edge
  __syncthreads();  // fwS ready

  float m = -INFINITY, ssum = 0.f, acc = 0.f;
  for (int base = i0; base <= i1; base += 4) {
    float l[4], vv[4];
    #pragma unroll
    for (int j = 0; j < 4; j++) {
      int i = base + j;
      if (i > i1) { l[j] = -INFINITY; vv[j] = 0.f; continue; }  // block-uniform
      long srow; const float* eap; float esc;
      if (i < i1) { srow = sbase + csr_src[i]; eap = ea + (long)csr_eid[i] * DE; esc = 1.f; }
      else        { srow = trow;               eap = meanea;                    esc = 1.f / E; }
      float kv = Kb[srow * H + tid];
      vv[j]    = Vb[srow * H + tid];
      float4 a0 = *(const float4*)(eap);
      float4 a1 = *(const float4*)(eap + 4);
      float a[DE] = {a0.x * esc, a0.y * esc, a0.z * esc, a0.w * esc,
                     a1.x * esc, a1.y * esc, a1.z * esc, a1.w * esc};
      float g = fbg, be = fbb;
      #pragma unroll
      for (int d = 0; d < DE; d++) {
        g  += a[d] * fwS[d][tid];
        be += a[d] * fwS[d][H + tid];
      }
      float p = q * (kv * (1.f + g) + be);
      p += __shfl_xor(p, 16);
      p += __shfl_xor(p, 8);
      p += __shfl_xor(p, 4);
      p += __shfl_xor(p, 2);
      p += __shfl_xor(p, 1);
      l[j] = p * scale;
    }
    float mn = m;
    #pragma unroll
    for (int j = 0; j < 4; j++) mn = fmaxf(mn, l[j]);
    float sc  = __expf(m - mn);
    float pe0 = __expf(l[0] - mn);
    float pe1 = __expf(l[1] - mn);
    float pe2 = __expf(l[2] - mn);
    float pe3 = __expf(l[3] - mn);
    ssum = ssum * sc + ((pe0 + pe1) + (pe2 + pe3));
    acc  = acc  * sc + ((pe0 * vv[0] + pe1 * vv[1]) + (pe2 * vv[2] + pe3 * vv[3]));
    m = mn;
  }
  float ab = acc / (ssum + 1e-16f);

  // ---- O-projection: y[c] = ob[c] + sum_k ab[k] * ow[k][c] ----
  __shared__ float sab[H];
  sab[tid] = ab;
  __syncthreads();
  float y = ob[tid];
  #pragma unroll 8
  for (int k = 0; k < H; k++) y += sab[k] * ow[k * H + tid];

  // ---- residual + layernorm ----
  float v = x[drow * H + tid] + y;
  float mu = blockSum128(v) * (1.f / H);
  float dv = v - mu;
  float var = blockSum128(dv * dv) * (1.f / H);
  float o = dv * rsqrtf(var + 1e-5f) * lng[tid] + lnb[tid];

  if (!do_head) {
    xo[drow * H + tid] = o;
  } else {
    float hv = o * hw[tid];
    float tot = blockSum128(hv);
    if (tid == 0) {
      float z = tot + hb[0];
      out[b * N + n] = fmaxf(z, 0.f) + log1pf(expf(-fabsf(z)));  // softplus
    }
  }
}

// ---------------- launch ----------------
extern "C" void kernel_launch(void* const* d_in, const int* in_sizes, int n_in,
                              void* d_out, int out_size, void* d_ws, size_t ws_size,
                              hipStream_t stream) {
  const float* xw   = (const float*)d_in[0];
  const int*   ei   = (const int*)d_in[1];
  const float* ea   = (const float*)d_in[2];
  const float* in_w = (const float*)d_in[3];
  const float* in_b = (const float*)d_in[4];
  const float* qw   = (const float*)d_in[5];
  const float* qb   = (const float*)d_in[6];
  const float* kw   = (const float*)d_in[7];
  const float* kb   = (const float*)d_in[8];
  const float* vw   = (const float*)d_in[9];
  const float* vb   = (const float*)d_in[10];
  const float* fw   = (const float*)d_in[11];
  const float* fb   = (const float*)d_in[12];
  const float* ow   = (const float*)d_in[13];
  const float* ob   = (const float*)d_in[14];
  const float* ln_g = (const float*)d_in[15];
  const float* ln_b = (const float*)d_in[16];
  const float* hw   = (const float*)d_in[17];
  const float* hb   = (const float*)d_in[18];
  float* out = (float*)d_out;

  // workspace carve-up
  float* ws   = (float*)d_ws;
  float* x    = ws;
  float* x2   = x  + (long)ROWS * H;
  float* Qb   = x2 + (long)ROWS * H;
  float* Kb   = Qb + (long)ROWS * H;
  float* Vb   = Kb + (long)ROWS * H;
  float* meanea  = Vb + (long)ROWS * H;   // 8 floats (zeroed by k_count_scan)
  int* offs    = (int*)(meanea + 8);
  int* cursor  = offs + N + 1;
  int* csr_src = cursor + N;
  int* csr_eid = csr_src + E;

  k_count_scan<<<1, 1024, 0, stream>>>(ei, offs, cursor, meanea);
  k_prep2<<<128, 256, 0, stream>>>(ei, ea, cursor, csr_src, csr_eid, meanea);

  float* xa = x;
  float* xb = x2;
  for (int l = 0; l < L; l++) {
    int in_lo = l, out_lo = l + 1;
    int rows_pb = (WL - in_lo) * N;
    int tpb = (rows_pb + 15) / 16;
    k_gemm<<<dim3(B * tpb, 3), H, 0, stream>>>(
        xa, xw, in_w, in_b,
        qw + (long)l * H * H, qb + (long)l * H, kw + (long)l * H * H, kb + (long)l * H,
        vw + (long)l * H * H, vb + (long)l * H, Qb, Kb, Vb, xa,
        in_lo * N, tpb, (l == 0) ? 1 : 0);
    int nout = B * (WL - out_lo) * N;
    int last = (l == L - 1) ? 1 : 0;
    k_attn_oln<<<nout, H, 0, stream>>>(
        Qb, Kb, Vb, ea, meanea,
        fw + (long)l * DE * 2 * H, fb + (long)l * 2 * H,
        offs, csr_src, csr_eid,
        xa, ow + (long)l * H * H, ob + (long)l * H,
        ln_g + (long)l * H, ln_b + (long)l * H, xb, out_lo,
        hw, hb, out, last);
    float* tmp = xa; xa = xb; xb = tmp;
  }
}